// Round 1
// baseline (583.768 us; speedup 1.0000x reference)
//
#include <hip/hip_runtime.h>
#include <math.h>

// Problem constants
#define D    256      // feature dim (= C)
#define K    1024     // codebook size
#define HWX  1024     // H*W
#define NPTS 32768    // B*H*W
#define PT   32       // points per block
#define KT   64       // code tile
#define DCH  64       // d chunk for e-tile staging
#define XS_STRIDE 1028  // (256*4 + 4) floats per point-group row -> 2-way (free) LDS access
#define ES_STRIDE 68    // 64 + 4 pad

#define Q_OFF   1
#define PERP_OFF (1 + 8388608)
#define ENC_OFF  (2 + 8388608)

// ws layout: enorm float[1024] @0 ; counts int[1024] @4096B ; loss_accum float @8192B

__global__ __launch_bounds__(256) void vq_prep(const float* __restrict__ emb,
                                               float* __restrict__ enorm,
                                               int* __restrict__ counts,
                                               float* __restrict__ loss_accum) {
  const int t = threadIdx.x;
  const int gid = blockIdx.x * 256 + t;
  const int w = gid >> 6;          // code id, 0..1023 (grid = 256 blocks)
  const int lane = t & 63;
  float4 v = *reinterpret_cast<const float4*>(emb + (size_t)w * D + lane * 4);
  float s = v.x * v.x + v.y * v.y + v.z * v.z + v.w * v.w;
#pragma unroll
  for (int off = 32; off > 0; off >>= 1) s += __shfl_down(s, off);
  if (lane == 0) enorm[w] = s;
  if (gid < K) counts[gid] = 0;
  if (gid == 0) *loss_accum = 0.0f;
}

#define STEP(XV, E0C, E1C)                                                     \
  acc[0][0] += XV.x * E0C; acc[1][0] += XV.y * E0C;                            \
  acc[2][0] += XV.z * E0C; acc[3][0] += XV.w * E0C;                            \
  acc[0][1] += XV.x * E1C; acc[1][1] += XV.y * E1C;                            \
  acc[2][1] += XV.z * E1C; acc[3][1] += XV.w * E1C;

__global__ __launch_bounds__(256) void vq_main(const float* __restrict__ x,
                                               const float* __restrict__ emb,
                                               const float* __restrict__ enorm,
                                               float* __restrict__ out_q,
                                               float* __restrict__ out_enc,
                                               float* __restrict__ loss_accum,
                                               int* __restrict__ counts) {
  __shared__ float xs[8 * XS_STRIDE];   // 32896 B: x tile [pg][d][j], full D
  __shared__ float es[KT * ES_STRIDE];  // 17408 B: e tile [kk][dl] (one d-chunk)
  __shared__ int idx_s[PT];

  const int t = threadIdx.x;
  const int p0 = blockIdx.x * PT;   // first point of this block
  const int bb = p0 >> 10;          // batch index
  const int hw0 = p0 & 1023;        // hw offset (PT-aligned)
  const int pg = t & 7;             // point group (4 points each)
  const int kg = t >> 3;            // 0..31, 2 codes each

  // ---- stage x tile: NCHW -> LDS [pg][d][j] (coalesced 128B segments) ----
  {
    const int pi = t & 31, c0 = t >> 5;
    const int xj = pi & 3, xpg = pi >> 2;
    const float* xb = x + (size_t)bb * D * HWX + hw0 + pi;
#pragma unroll
    for (int c = c0; c < D; c += 8)
      xs[xpg * XS_STRIDE + c * 4 + xj] = xb[(size_t)c * HWX];
  }

  float minval[4];
  int minidx[4];
#pragma unroll
  for (int j = 0; j < 4; ++j) { minval[j] = 3.4e38f; minidx[j] = 0; }

  for (int kt = 0; kt < K / KT; ++kt) {
    const int k0 = kt * KT;
    float acc[4][2] = {{0.f, 0.f}, {0.f, 0.f}, {0.f, 0.f}, {0.f, 0.f}};
    for (int dc = 0; dc < D; dc += DCH) {
      __syncthreads();  // protect es from prior readers (also orders xs staging)
      {                 // stage e chunk: 64 codes x 64 d, float4 both sides
        const int dl = (t & 15) * 4;
        const int kk0 = t >> 4;
#pragma unroll
        for (int kk = kk0; kk < KT; kk += 16) {
          float4 v = *reinterpret_cast<const float4*>(emb + (size_t)(k0 + kk) * D + dc + dl);
          *reinterpret_cast<float4*>(&es[kk * ES_STRIDE + dl]) = v;
        }
      }
      __syncthreads();
      const float* xsb = xs + pg * XS_STRIDE + dc * 4;
      const float* es0 = es + (kg * 2) * ES_STRIDE;
      const float* es1 = es0 + ES_STRIDE;
#pragma unroll
      for (int dd = 0; dd < DCH; dd += 4) {
        const float4 e0 = *reinterpret_cast<const float4*>(es0 + dd);
        const float4 e1 = *reinterpret_cast<const float4*>(es1 + dd);
        const float4 x0 = *reinterpret_cast<const float4*>(xsb + (dd + 0) * 4);
        const float4 x1 = *reinterpret_cast<const float4*>(xsb + (dd + 1) * 4);
        const float4 x2 = *reinterpret_cast<const float4*>(xsb + (dd + 2) * 4);
        const float4 x3 = *reinterpret_cast<const float4*>(xsb + (dd + 3) * 4);
        STEP(x0, e0.x, e1.x)
        STEP(x1, e0.y, e1.y)
        STEP(x2, e0.z, e1.z)
        STEP(x3, e0.w, e1.w)
      }
    }
    // argmin update (x-norm is row-constant, irrelevant for argmin)
    const float en0 = enorm[k0 + kg * 2];
    const float en1 = enorm[k0 + kg * 2 + 1];
#pragma unroll
    for (int j = 0; j < 4; ++j) {
      const float m0 = en0 - 2.0f * acc[j][0];
      if (m0 < minval[j]) { minval[j] = m0; minidx[j] = k0 + kg * 2; }
      const float m1 = en1 - 2.0f * acc[j][1];
      if (m1 < minval[j]) { minval[j] = m1; minidx[j] = k0 + kg * 2 + 1; }
    }
  }

  // ---- cross-kg reduction (red arrays alias es) ----
  __syncthreads();
  float* red_val = es;                     // [32 kg][32 pi]
  int* red_idx = (int*)(es + 32 * PT);
#pragma unroll
  for (int j = 0; j < 4; ++j) {
    red_val[kg * PT + pg * 4 + j] = minval[j];
    red_idx[kg * PT + pg * 4 + j] = minidx[j];
  }
  __syncthreads();
  float dist = 0.0f;
  if (t < PT) {
    const int pi = t;
    float bv = red_val[pi];
    int bi = red_idx[pi];
    for (int g = 1; g < 32; ++g) {
      const float v = red_val[g * PT + pi];
      const int iv = red_idx[g * PT + pi];
      if (v < bv || (v == bv && iv < bi)) { bv = v; bi = iv; }  // first-index tie-break
    }
    // x-norm from LDS (conflict-free: bank = (pi + 4d) % 32)
    float xn = 0.0f;
    const float* xp = xs + (pi >> 2) * XS_STRIDE + (pi & 3);
    for (int d = 0; d < D; ++d) { const float xv = xp[d * 4]; xn += xv * xv; }
    dist = bv + xn;  // = ||x||^2 + ||e||^2 - 2 x.e
    idx_s[pi] = bi;
    atomicAdd(&counts[bi], 1);
  }
  if (t < 64) {  // full wave 0: lanes 32..63 contribute 0
#pragma unroll
    for (int off = 32; off > 0; off >>= 1) dist += __shfl_down(dist, off);
    if (t == 0) atomicAdd(loss_accum, dist);
  }
  __syncthreads();

  // ---- quantized output, NCHW (coalesced stores; emb gather is L1/L2-hot) ----
  {
    const int pi = t & 31, c0 = t >> 5;
    const int row = idx_s[pi];
    const float* er = emb + (size_t)row * D;
    float* qb = out_q + (size_t)bb * D * HWX + hw0 + pi;
#pragma unroll
    for (int c = c0; c < D; c += 8) qb[(size_t)c * HWX] = er[c];
  }
  // ---- one-hot encodings (float2: enc region is only 8B-aligned) ----
  {
    float2* eb = reinterpret_cast<float2*>(out_enc + (size_t)p0 * K);
#pragma unroll 4
    for (int i = t; i < PT * K / 2; i += 256) {
      const int row = i >> 9;
      const int c2 = (i & 511) * 2;
      const int target = idx_s[row];
      float2 v = make_float2(0.f, 0.f);
      if (target == c2) v.x = 1.0f;
      else if (target == c2 + 1) v.y = 1.0f;
      eb[i] = v;
    }
  }
}

__global__ __launch_bounds__(256) void vq_final(const int* __restrict__ counts,
                                                const float* __restrict__ loss_accum,
                                                float* __restrict__ out) {
  __shared__ float sh[4];
  const int t = threadIdx.x;
  float s = 0.0f;
  for (int k = t; k < K; k += 256) {
    const float p = (float)counts[k] * (1.0f / 32768.0f);
    s += p * logf(p + 1e-10f);  // p==0 -> contributes 0
  }
#pragma unroll
  for (int off = 32; off > 0; off >>= 1) s += __shfl_down(s, off);
  if ((t & 63) == 0) sh[t >> 6] = s;
  __syncthreads();
  if (t == 0) {
    const float tot = sh[0] + sh[1] + sh[2] + sh[3];
    out[PERP_OFF] = expf(-tot);
    out[0] = 0.25f * (*loss_accum) / 8388608.0f;
  }
}

extern "C" void kernel_launch(void* const* d_in, const int* in_sizes, int n_in,
                              void* d_out, int out_size, void* d_ws, size_t ws_size,
                              hipStream_t stream) {
  const float* x = (const float*)d_in[0];     // [32,256,32,32] fp32 NCHW
  const float* emb = (const float*)d_in[1];   // [1024,256] fp32
  float* out = (float*)d_out;
  float* enorm = (float*)d_ws;
  int* counts = (int*)((char*)d_ws + 4096);
  float* loss_accum = (float*)((char*)d_ws + 8192);

  hipLaunchKernelGGL(vq_prep, dim3(256), dim3(256), 0, stream,
                     emb, enorm, counts, loss_accum);
  hipLaunchKernelGGL(vq_main, dim3(NPTS / PT), dim3(256), 0, stream,
                     x, emb, enorm, out + Q_OFF, out + ENC_OFF, loss_accum, counts);
  hipLaunchKernelGGL(vq_final, dim3(1), dim3(256), 0, stream,
                     counts, loss_accum, out);
}